// Round 4
// baseline (116.448 us; speedup 1.0000x reference)
//
#include <hip/hip_runtime.h>
#include <stdint.h>

// Top-k (k=50) temperature sampling, bit-matching
// jax.random.categorical(key(42), topk_mask(logits/T, 50)) with
// jax_threefry_partitionable=True.
//
// Round-7 structure: one 1024-thread block per row, ONE data scan with ALL
// per-thread loads (12 unconditional + 1 predicated float4) issued up front
// into registers, pinned above their uses by an asm memory barrier.
// Round-6 post-mortem: source-level 4-wide batching left VGPR_Count at 28 ->
// the compiler sank each load into its consumer, serializing them (1
// outstanding load/wave -> ~4 GB/s/CU by Little's law -> 47 us scan). This
// version holds ~13 KB/wave in flight (~208 KB/CU), enough to stream at the
// per-CU HBM rate (~25 GB/s/CU -> ~8-10 us scan floor).
//
//   Hot pass: collect indices of elements with raw logit >= 10.0 (plain
//     float compare; division by positive T is monotone so raw order ==
//     scaled order). The 50th of 50257 N(0,16) draws sits at 12.36 +- 0.17,
//     so cutoff 10.0 captures the full top-50 with ~14-sigma margin while
//     collecting only ~312 candidates.
//   Refine (unchanged numerics): exact IEEE s = l/T keys, exact
//     (s_key, index) rank -> rank < K membership (lax.top_k low-index tie
//     rule), partitionable-threefry gumbel, argmax with low-index ties.
//   Exactness guards (both block-uniform, never trip on bench data):
//     (a) K <= count <= CAND_CAP  -> candidate set is a superset of top-K
//         (any non-candidate has s <= 10.0/T by monotone rounded division);
//     (b) the rank-(K-1) candidate's s-key must be STRICTLY > fkey(10.0/T)
//         so no sub-cutoff element can tie into top-K via a lower index.
//   If either guard fails: full original two-scan histogram path runs as
//   fallback (exact for arbitrary inputs).

#define VOCAB 50257
#define BATCH 256
#define NT 1024
#define NBINS 4096
#define CAND_CAP 2048
#define FILTER_VAL 4.0f
#define SPEC_VAL 10.0f

__device__ __forceinline__ uint32_t rotl32(uint32_t v, int r) {
  return (v << r) | (v >> (32 - r));
}

// JAX Threefry-2x32-20, key = (0, 42)
__device__ __forceinline__ void threefry2x32_42(uint32_t& x0, uint32_t& x1) {
  const uint32_t ks0 = 0u;
  const uint32_t ks1 = 42u;
  const uint32_t ks2 = ks0 ^ ks1 ^ 0x1BD11BDAu;
  x0 += ks0; x1 += ks1;
#define TF_R(r) { x0 += x1; x1 = rotl32(x1, (r)); x1 ^= x0; }
  TF_R(13) TF_R(15) TF_R(26) TF_R(6)
  x0 += ks1; x1 += ks2 + 1u;
  TF_R(17) TF_R(29) TF_R(16) TF_R(24)
  x0 += ks2; x1 += ks0 + 2u;
  TF_R(13) TF_R(15) TF_R(26) TF_R(6)
  x0 += ks0; x1 += ks1 + 3u;
  TF_R(17) TF_R(29) TF_R(16) TF_R(24)
  x0 += ks1; x1 += ks2 + 4u;
  TF_R(13) TF_R(15) TF_R(26) TF_R(6)
  x0 += ks2; x1 += ks0 + 5u;
#undef TF_R
}

// Gumbel noise at flat index i, jax_threefry_partitionable=True:
// counter = u64 flat index -> (hi32=0, lo32=i), bits = out0 ^ out1.
__device__ __forceinline__ float gumbel_at(uint32_t flat) {
  uint32_t x0 = 0u, x1 = flat;
  threefry2x32_42(x0, x1);
  uint32_t bits = x0 ^ x1;
  uint32_t fb = (bits >> 9) | 0x3f800000u;
  float f = __uint_as_float(fb) - 1.0f;          // exact
  float u = fmaxf(f, 1.17549435e-38f);
  float t = (float)log((double)u);               // correctly-rounded fp32 path
  float g = (float)(-log((double)(-t)));
  return g;
}

// Monotone float->uint32 key (no NaNs in data).
__device__ __forceinline__ uint32_t fkey(float x) {
  uint32_t u = __float_as_uint(x);
  return (u & 0x80000000u) ? ~u : (u | 0x80000000u);
}

extern "C" __global__ void __launch_bounds__(NT, 4)
topk_sample_kernel(const float* __restrict__ logits,
                   const float* __restrict__ temp_p,
                   const int* __restrict__ topk_p,
                   int* __restrict__ out) {
  const int row = blockIdx.x;
  const int tid = threadIdx.x;
  const float temp = temp_p[0];
  const int K = topk_p[0];
  const float* rowp = logits + (size_t)row * VOCAB;

  // rows are only 4B-aligned (VOCAB*4 % 16 == 4): scalar prologue to 16B.
  const int pc = (4 - (row & 3)) & 3;
  const int nv4 = (VOCAB - pc) >> 2;         // 12563 or 12564
  const int tailbase = pc + (nv4 << 2);
  const int tailc = VOCAB - tailbase;        // 0..3
  const float4* body = (const float4*)(rowp + pc);

  __shared__ unsigned hist[NBINS];
  __shared__ unsigned wtot[16];
  __shared__ unsigned aboveWave[16];
  __shared__ int sh_tb, sh_total, sh_cnt, sh_ok;
  __shared__ unsigned ckey[CAND_CAP];
  __shared__ int cidx[CAND_CAP];
  __shared__ float wbv[16];
  __shared__ int wbi[16];

  const int lane = tid & 63;
  const int wave = tid >> 6;

  float bestv = -__builtin_huge_valf();
  int besti = 0x7fffffff;
  bool done = false;

  // ---- Hot pass: single scan, all loads issued up front ----
  if (tid == 0) { sh_cnt = 0; sh_ok = 0; }
  __syncthreads();
  if (tid < pc) {
    if (rowp[tid] >= SPEC_VAL) {
      int p = atomicAdd(&sh_cnt, 1);
      if (p < CAND_CAP) cidx[p] = tid;
    }
  }
  // Per-thread coverage: v = tid + k*NT, k = 0..11 always valid
  // (tid_max + 11*NT = 1023 + 11264 = 12287 < 12563 <= nv4), k = 12
  // valid only for tid < nv4 - 12*NT (~276 threads).
  {
    float4 r0  = body[tid];
    float4 r1  = body[tid + 1 * NT];
    float4 r2  = body[tid + 2 * NT];
    float4 r3  = body[tid + 3 * NT];
    float4 r4  = body[tid + 4 * NT];
    float4 r5  = body[tid + 5 * NT];
    float4 r6  = body[tid + 6 * NT];
    float4 r7  = body[tid + 7 * NT];
    float4 r8  = body[tid + 8 * NT];
    float4 r9  = body[tid + 9 * NT];
    float4 r10 = body[tid + 10 * NT];
    float4 r11 = body[tid + 11 * NT];
    const int v12 = tid + 12 * NT;
    float4 r12;
    if (v12 < nv4) {
      r12 = body[v12];
    } else {
      r12.x = r12.y = r12.z = r12.w = -3.0e38f;  // sentinel: never >= SPEC_VAL
    }
    // Pin all 13 loads above their uses: the asm may read/write any memory,
    // so loads cannot sink below it and the LDS atomics cannot hoist above.
    asm volatile("" ::: "memory");
#define PROC4(VX, b)                                                             \
    {                                                                            \
      int base_ = (b);                                                           \
      if (VX.x >= SPEC_VAL) { int p = atomicAdd(&sh_cnt, 1); if (p < CAND_CAP) cidx[p] = base_; }     \
      if (VX.y >= SPEC_VAL) { int p = atomicAdd(&sh_cnt, 1); if (p < CAND_CAP) cidx[p] = base_ + 1; } \
      if (VX.z >= SPEC_VAL) { int p = atomicAdd(&sh_cnt, 1); if (p < CAND_CAP) cidx[p] = base_ + 2; } \
      if (VX.w >= SPEC_VAL) { int p = atomicAdd(&sh_cnt, 1); if (p < CAND_CAP) cidx[p] = base_ + 3; } \
    }
    PROC4(r0,  pc + (tid << 2))
    PROC4(r1,  pc + ((tid + 1 * NT) << 2))
    PROC4(r2,  pc + ((tid + 2 * NT) << 2))
    PROC4(r3,  pc + ((tid + 3 * NT) << 2))
    PROC4(r4,  pc + ((tid + 4 * NT) << 2))
    PROC4(r5,  pc + ((tid + 5 * NT) << 2))
    PROC4(r6,  pc + ((tid + 6 * NT) << 2))
    PROC4(r7,  pc + ((tid + 7 * NT) << 2))
    PROC4(r8,  pc + ((tid + 8 * NT) << 2))
    PROC4(r9,  pc + ((tid + 9 * NT) << 2))
    PROC4(r10, pc + ((tid + 10 * NT) << 2))
    PROC4(r11, pc + ((tid + 11 * NT) << 2))
    PROC4(r12, pc + (v12 << 2))
#undef PROC4
  }
  if (tid < tailc) {
    if (rowp[tailbase + tid] >= SPEC_VAL) {
      int p = atomicAdd(&sh_cnt, 1);
      if (p < CAND_CAP) cidx[p] = tailbase + tid;
    }
  }
  __syncthreads();
  const int total = sh_cnt;                  // block-uniform

  if (total >= K && total <= CAND_CAP) {     // guard (a): superset of top-K
    const int C = total;
    float s_mine = 0.0f;
    if (tid < C) {
      s_mine = rowp[cidx[tid]] / temp;       // IEEE fp32 div, matches reference
      ckey[tid] = fkey(s_mine);
    }
    __syncthreads();
    if (tid < C) {
      const uint32_t mk = ckey[tid];
      const int mi = cidx[tid];
      int rank = 0;
      for (int j = 0; j < C; ++j) {
        uint32_t k = ckey[j];
        rank += (k > mk || (k == mk && cidx[j] < mi)) ? 1 : 0;
      }
      if (rank == K - 1) {
        // guard (b): K-th s-key strictly above the cutoff's s-key =>
        // no element below SPEC_VAL can reach or tie the top-K boundary.
        sh_ok = (mk > fkey(SPEC_VAL / temp)) ? 1 : 0;
      }
      if (rank < K) {                        // exact lax.top_k membership
        float v2 = s_mine + gumbel_at((uint32_t)row * (uint32_t)VOCAB + (uint32_t)mi);
        bestv = v2; besti = mi;
      }
    }
    __syncthreads();
    if (sh_ok) {
      done = true;                           // block-uniform
    } else {
      bestv = -__builtin_huge_valf();        // discard, take fallback
      besti = 0x7fffffff;
    }
  }

  // ---- Fallback: two-scan histogram path (never taken on bench data;
  //      exact for arbitrary inputs). ----
  if (!done) {
    uint32_t filt = fkey(FILTER_VAL);
    int tb = 0;
    for (;;) {
      for (int b = tid; b < NBINS; b += NT) hist[b] = 0u;
      __syncthreads();
      if (tid < pc) {
        uint32_t k = fkey(rowp[tid]);
        if (k >= filt) atomicAdd(&hist[k >> 20], 1u);
      }
      for (int w = tid; w < nv4; w += NT) {
        float4 x = body[w];
        uint32_t k0 = fkey(x.x), k1 = fkey(x.y), k2 = fkey(x.z), k3 = fkey(x.w);
        if (k0 >= filt) atomicAdd(&hist[k0 >> 20], 1u);
        if (k1 >= filt) atomicAdd(&hist[k1 >> 20], 1u);
        if (k2 >= filt) atomicAdd(&hist[k2 >> 20], 1u);
        if (k3 >= filt) atomicAdd(&hist[k3 >> 20], 1u);
      }
      if (tid < tailc) {
        uint32_t k = fkey(rowp[tailbase + tid]);
        if (k >= filt) atomicAdd(&hist[k >> 20], 1u);
      }
      __syncthreads();

      unsigned p = hist[4 * tid] + hist[4 * tid + 1] + hist[4 * tid + 2] + hist[4 * tid + 3];
      unsigned vv = p;
      for (int off = 1; off < 64; off <<= 1) {
        unsigned o = (unsigned)__shfl_down((int)vv, off);
        if (lane + off < 64) vv += o;      // inclusive suffix sum within wave
      }
      if (lane == 0) wtot[wave] = vv;
      __syncthreads();
      if (tid == 0) {
        unsigned acc = 0;
        for (int w = 15; w >= 0; --w) { aboveWave[w] = acc; acc += wtot[w]; }
        sh_total = (int)acc;
      }
      __syncthreads();
      unsigned above = aboveWave[wave] + (vv - p);
      if (above < (unsigned)K && above + p >= (unsigned)K) {
        int need = K - (int)above;
        for (int b = 3; b >= 0; --b) {
          unsigned c = hist[4 * tid + b];
          if (c >= (unsigned)need) { sh_tb = 4 * tid + b; break; }
          need -= (int)c;
        }
      }
      __syncthreads();
      if (sh_total >= K) { tb = sh_tb; break; }
      filt = 0u;
      __syncthreads();
    }

    const uint32_t cutk = (uint32_t)max(tb - 1, 0) << 20;
    if (tid == 0) sh_cnt = 0;
    __syncthreads();
    if (tid < pc) {
      if (fkey(rowp[tid]) >= cutk) {
        int p = atomicAdd(&sh_cnt, 1);
        if (p < CAND_CAP) cidx[p] = tid;
      }
    }
    for (int w = tid; w < nv4; w += NT) {
      float4 x = body[w];
      int base = pc + (w << 2);
      if (fkey(x.x) >= cutk) { int p = atomicAdd(&sh_cnt, 1); if (p < CAND_CAP) cidx[p] = base; }
      if (fkey(x.y) >= cutk) { int p = atomicAdd(&sh_cnt, 1); if (p < CAND_CAP) cidx[p] = base + 1; }
      if (fkey(x.z) >= cutk) { int p = atomicAdd(&sh_cnt, 1); if (p < CAND_CAP) cidx[p] = base + 2; }
      if (fkey(x.w) >= cutk) { int p = atomicAdd(&sh_cnt, 1); if (p < CAND_CAP) cidx[p] = base + 3; }
    }
    if (tid < tailc) {
      if (fkey(rowp[tailbase + tid]) >= cutk) {
        int p = atomicAdd(&sh_cnt, 1);
        if (p < CAND_CAP) cidx[p] = tailbase + tid;
      }
    }
    __syncthreads();
    const int C = min(sh_cnt, CAND_CAP);

    if (tid < C) {
      int idx = cidx[tid];
      float s = rowp[idx] / temp;
      ckey[tid] = fkey(s);
    }
    __syncthreads();

    if (tid < C) {
      const uint32_t mk = ckey[tid];
      const int mi = cidx[tid];
      int rank = 0;
      for (int j = 0; j < C; ++j) {
        uint32_t k = ckey[j];
        rank += (k > mk || (k == mk && cidx[j] < mi)) ? 1 : 0;
      }
      if (rank < K) {
        float s = rowp[mi] / temp;
        float v2 = s + gumbel_at((uint32_t)row * (uint32_t)VOCAB + (uint32_t)mi);
        bestv = v2; besti = mi;
      }
    }
    __syncthreads();
  }

  // ---- Common argmax reduction: wave shuffle + 16-way LDS combine ----
  for (int off = 32; off > 0; off >>= 1) {
    float v2 = __shfl_down(bestv, off);
    int i2 = __shfl_down(besti, off);
    if (v2 > bestv || (v2 == bestv && i2 < besti)) { bestv = v2; besti = i2; }
  }
  if (lane == 0) { wbv[wave] = bestv; wbi[wave] = besti; }
  __syncthreads();
  if (tid == 0) {
    float bv = wbv[0];
    int bi = wbi[0];
    for (int w = 1; w < 16; ++w) {
      float v2 = wbv[w];
      int i2 = wbi[w];
      if (v2 > bv || (v2 == bv && i2 < bi)) { bv = v2; bi = i2; }
    }
    out[row] = bi;
  }
}

extern "C" void kernel_launch(void* const* d_in, const int* in_sizes, int n_in,
                              void* d_out, int out_size, void* d_ws, size_t ws_size,
                              hipStream_t stream) {
  const float* logits = (const float*)d_in[0];
  const float* temp_p = (const float*)d_in[1];
  const int* topk_p = (const int*)d_in[2];
  int* out = (int*)d_out;
  hipLaunchKernelGGL(topk_sample_kernel, dim3(BATCH), dim3(NT), 0, stream,
                     logits, temp_p, topk_p, out);
}

// Round 5
// 115.072 us; speedup vs baseline: 1.0120x; 1.0120x over previous
//
#include <hip/hip_runtime.h>
#include <stdint.h>

// Top-k (k=50) temperature sampling, bit-matching
// jax.random.categorical(key(42), topk_mask(logits/T, 50)) with
// jax_threefry_partitionable=True.
//
// Round-8 structure: one 1024-thread block per row, ONE data scan. The 13
// per-thread float4 loads are emitted as inline-asm global_load_dwordx4
// with distinct register outputs -> the compiler CANNOT re-roll or
// serialize them (rounds 6/7 proved source-level batching gets undone:
// VGPR stayed 28/36, dur stuck at 45us = ~1 outstanding load/CU = 600 GB/s
// by Little's law). All 13 issue back-to-back (13 KB in flight per wave,
// ~208 KB/CU), then a single s_waitcnt vmcnt(0) + sched_barrier, then
// branch-free processing.
//
//   Hot pass: collect indices of elements with raw logit >= 10.0 (plain
//     float compare; division by positive T is monotone so raw order ==
//     scaled order). The 50th of 50257 N(0,16) draws sits at 12.36 +- 0.17,
//     so cutoff 10.0 captures the full top-50 with ~14-sigma margin while
//     collecting only ~312 candidates.
//   Refine (unchanged numerics): exact IEEE s = l/T keys, exact
//     (s_key, index) rank -> rank < K membership (lax.top_k low-index tie
//     rule), partitionable-threefry gumbel, argmax with low-index ties.
//   Exactness guards (both block-uniform, never trip on bench data):
//     (a) K <= count <= CAND_CAP  -> candidate set is a superset of top-K
//         (any non-candidate has s <= 10.0/T by monotone rounded division);
//     (b) the rank-(K-1) candidate's s-key must be STRICTLY > fkey(10.0/T)
//         so no sub-cutoff element can tie into top-K via a lower index.
//   If either guard fails: full original two-scan histogram path runs as
//   fallback (exact for arbitrary inputs).

#define VOCAB 50257
#define BATCH 256
#define NT 1024
#define NBINS 4096
#define CAND_CAP 2048
#define FILTER_VAL 4.0f
#define SPEC_VAL 10.0f

typedef float v4f __attribute__((ext_vector_type(4)));

__device__ __forceinline__ uint32_t rotl32(uint32_t v, int r) {
  return (v << r) | (v >> (32 - r));
}

// JAX Threefry-2x32-20, key = (0, 42)
__device__ __forceinline__ void threefry2x32_42(uint32_t& x0, uint32_t& x1) {
  const uint32_t ks0 = 0u;
  const uint32_t ks1 = 42u;
  const uint32_t ks2 = ks0 ^ ks1 ^ 0x1BD11BDAu;
  x0 += ks0; x1 += ks1;
#define TF_R(r) { x0 += x1; x1 = rotl32(x1, (r)); x1 ^= x0; }
  TF_R(13) TF_R(15) TF_R(26) TF_R(6)
  x0 += ks1; x1 += ks2 + 1u;
  TF_R(17) TF_R(29) TF_R(16) TF_R(24)
  x0 += ks2; x1 += ks0 + 2u;
  TF_R(13) TF_R(15) TF_R(26) TF_R(6)
  x0 += ks0; x1 += ks1 + 3u;
  TF_R(17) TF_R(29) TF_R(16) TF_R(24)
  x0 += ks1; x1 += ks2 + 4u;
  TF_R(13) TF_R(15) TF_R(26) TF_R(6)
  x0 += ks2; x1 += ks0 + 5u;
#undef TF_R
}

// Gumbel noise at flat index i, jax_threefry_partitionable=True:
// counter = u64 flat index -> (hi32=0, lo32=i), bits = out0 ^ out1.
__device__ __forceinline__ float gumbel_at(uint32_t flat) {
  uint32_t x0 = 0u, x1 = flat;
  threefry2x32_42(x0, x1);
  uint32_t bits = x0 ^ x1;
  uint32_t fb = (bits >> 9) | 0x3f800000u;
  float f = __uint_as_float(fb) - 1.0f;          // exact
  float u = fmaxf(f, 1.17549435e-38f);
  float t = (float)log((double)u);               // correctly-rounded fp32 path
  float g = (float)(-log((double)(-t)));
  return g;
}

// Monotone float->uint32 key (no NaNs in data).
__device__ __forceinline__ uint32_t fkey(float x) {
  uint32_t u = __float_as_uint(x);
  return (u & 0x80000000u) ? ~u : (u | 0x80000000u);
}

extern "C" __global__ void __launch_bounds__(NT, 4)
topk_sample_kernel(const float* __restrict__ logits,
                   const float* __restrict__ temp_p,
                   const int* __restrict__ topk_p,
                   int* __restrict__ out) {
  const int row = blockIdx.x;
  const int tid = threadIdx.x;
  const float temp = temp_p[0];
  const int K = topk_p[0];
  const float* rowp = logits + (size_t)row * VOCAB;

  // rows are only 4B-aligned (VOCAB*4 % 16 == 4): scalar prologue to 16B.
  const int pc = (4 - (row & 3)) & 3;
  const int nv4 = (VOCAB - pc) >> 2;         // 12563 or 12564
  const int tailbase = pc + (nv4 << 2);
  const int tailc = VOCAB - tailbase;        // 0..3
  const float4* body = (const float4*)(rowp + pc);

  __shared__ unsigned hist[NBINS];
  __shared__ unsigned wtot[16];
  __shared__ unsigned aboveWave[16];
  __shared__ int sh_tb, sh_total, sh_cnt, sh_ok;
  __shared__ unsigned ckey[CAND_CAP];
  __shared__ int cidx[CAND_CAP];
  __shared__ float wbv[16];
  __shared__ int wbi[16];

  const int lane = tid & 63;
  const int wave = tid >> 6;

  float bestv = -__builtin_huge_valf();
  int besti = 0x7fffffff;
  bool done = false;

  // ---- Hot pass: single scan, 13 loads issued via volatile inline asm ----
  if (tid == 0) { sh_cnt = 0; sh_ok = 0; }
  __syncthreads();
  if (tid < pc) {
    if (rowp[tid] >= SPEC_VAL) {
      int p = atomicAdd(&sh_cnt, 1);
      if (p < CAND_CAP) cidx[p] = tid;
    }
  }
  // Per-thread coverage: v = tid + k*NT, k = 0..11 always valid
  // (1023 + 11*1024 = 12287 < 12563 <= nv4); k = 12 valid only for
  // tid < nv4 - 12*NT (~276-300 threads) -> clamped addr + sentinel.
  {
    const int v12 = tid + 12 * NT;
    const bool has12 = (v12 < nv4);
    const float4* a12 = body + (has12 ? v12 : 0);

    v4f r0, r1, r2, r3, r4, r5, r6, r7, r8, r9, r10, r11, r12;
#define GLD(dst, addr) \
    asm volatile("global_load_dwordx4 %0, %1, off" : "=v"(dst) : "v"(addr))
    GLD(r0,  body + tid);
    GLD(r1,  body + (tid + 1 * NT));
    GLD(r2,  body + (tid + 2 * NT));
    GLD(r3,  body + (tid + 3 * NT));
    GLD(r4,  body + (tid + 4 * NT));
    GLD(r5,  body + (tid + 5 * NT));
    GLD(r6,  body + (tid + 6 * NT));
    GLD(r7,  body + (tid + 7 * NT));
    GLD(r8,  body + (tid + 8 * NT));
    GLD(r9,  body + (tid + 9 * NT));
    GLD(r10, body + (tid + 10 * NT));
    GLD(r11, body + (tid + 11 * NT));
    GLD(r12, a12);
#undef GLD
    asm volatile("s_waitcnt vmcnt(0)" ::: "memory");
    __builtin_amdgcn_sched_barrier(0);   // rule 18: no use hoists above the wait

    if (!has12) { r12[0] = r12[1] = r12[2] = r12[3] = -3.0e38f; }  // sentinel

#define PROC4(VX, b)                                                             \
    {                                                                            \
      int base_ = (b);                                                           \
      if (VX[0] >= SPEC_VAL) { int p = atomicAdd(&sh_cnt, 1); if (p < CAND_CAP) cidx[p] = base_; }     \
      if (VX[1] >= SPEC_VAL) { int p = atomicAdd(&sh_cnt, 1); if (p < CAND_CAP) cidx[p] = base_ + 1; } \
      if (VX[2] >= SPEC_VAL) { int p = atomicAdd(&sh_cnt, 1); if (p < CAND_CAP) cidx[p] = base_ + 2; } \
      if (VX[3] >= SPEC_VAL) { int p = atomicAdd(&sh_cnt, 1); if (p < CAND_CAP) cidx[p] = base_ + 3; } \
    }
    PROC4(r0,  pc + (tid << 2))
    PROC4(r1,  pc + ((tid + 1 * NT) << 2))
    PROC4(r2,  pc + ((tid + 2 * NT) << 2))
    PROC4(r3,  pc + ((tid + 3 * NT) << 2))
    PROC4(r4,  pc + ((tid + 4 * NT) << 2))
    PROC4(r5,  pc + ((tid + 5 * NT) << 2))
    PROC4(r6,  pc + ((tid + 6 * NT) << 2))
    PROC4(r7,  pc + ((tid + 7 * NT) << 2))
    PROC4(r8,  pc + ((tid + 8 * NT) << 2))
    PROC4(r9,  pc + ((tid + 9 * NT) << 2))
    PROC4(r10, pc + ((tid + 10 * NT) << 2))
    PROC4(r11, pc + ((tid + 11 * NT) << 2))
    PROC4(r12, pc + (v12 << 2))
#undef PROC4
  }
  if (tid < tailc) {
    if (rowp[tailbase + tid] >= SPEC_VAL) {
      int p = atomicAdd(&sh_cnt, 1);
      if (p < CAND_CAP) cidx[p] = tailbase + tid;
    }
  }
  __syncthreads();
  const int total = sh_cnt;                  // block-uniform

  if (total >= K && total <= CAND_CAP) {     // guard (a): superset of top-K
    const int C = total;
    float s_mine = 0.0f;
    if (tid < C) {
      s_mine = rowp[cidx[tid]] / temp;       // IEEE fp32 div, matches reference
      ckey[tid] = fkey(s_mine);
    }
    __syncthreads();
    if (tid < C) {
      const uint32_t mk = ckey[tid];
      const int mi = cidx[tid];
      int rank = 0;
      for (int j = 0; j < C; ++j) {
        uint32_t k = ckey[j];
        rank += (k > mk || (k == mk && cidx[j] < mi)) ? 1 : 0;
      }
      if (rank == K - 1) {
        // guard (b): K-th s-key strictly above the cutoff's s-key =>
        // no element below SPEC_VAL can reach or tie the top-K boundary.
        sh_ok = (mk > fkey(SPEC_VAL / temp)) ? 1 : 0;
      }
      if (rank < K) {                        // exact lax.top_k membership
        float v2 = s_mine + gumbel_at((uint32_t)row * (uint32_t)VOCAB + (uint32_t)mi);
        bestv = v2; besti = mi;
      }
    }
    __syncthreads();
    if (sh_ok) {
      done = true;                           // block-uniform
    } else {
      bestv = -__builtin_huge_valf();        // discard, take fallback
      besti = 0x7fffffff;
    }
  }

  // ---- Fallback: two-scan histogram path (never taken on bench data;
  //      exact for arbitrary inputs). ----
  if (!done) {
    uint32_t filt = fkey(FILTER_VAL);
    int tb = 0;
    for (;;) {
      for (int b = tid; b < NBINS; b += NT) hist[b] = 0u;
      __syncthreads();
      if (tid < pc) {
        uint32_t k = fkey(rowp[tid]);
        if (k >= filt) atomicAdd(&hist[k >> 20], 1u);
      }
      for (int w = tid; w < nv4; w += NT) {
        float4 x = body[w];
        uint32_t k0 = fkey(x.x), k1 = fkey(x.y), k2 = fkey(x.z), k3 = fkey(x.w);
        if (k0 >= filt) atomicAdd(&hist[k0 >> 20], 1u);
        if (k1 >= filt) atomicAdd(&hist[k1 >> 20], 1u);
        if (k2 >= filt) atomicAdd(&hist[k2 >> 20], 1u);
        if (k3 >= filt) atomicAdd(&hist[k3 >> 20], 1u);
      }
      if (tid < tailc) {
        uint32_t k = fkey(rowp[tailbase + tid]);
        if (k >= filt) atomicAdd(&hist[k >> 20], 1u);
      }
      __syncthreads();

      unsigned p = hist[4 * tid] + hist[4 * tid + 1] + hist[4 * tid + 2] + hist[4 * tid + 3];
      unsigned vv = p;
      for (int off = 1; off < 64; off <<= 1) {
        unsigned o = (unsigned)__shfl_down((int)vv, off);
        if (lane + off < 64) vv += o;      // inclusive suffix sum within wave
      }
      if (lane == 0) wtot[wave] = vv;
      __syncthreads();
      if (tid == 0) {
        unsigned acc = 0;
        for (int w = 15; w >= 0; --w) { aboveWave[w] = acc; acc += wtot[w]; }
        sh_total = (int)acc;
      }
      __syncthreads();
      unsigned above = aboveWave[wave] + (vv - p);
      if (above < (unsigned)K && above + p >= (unsigned)K) {
        int need = K - (int)above;
        for (int b = 3; b >= 0; --b) {
          unsigned c = hist[4 * tid + b];
          if (c >= (unsigned)need) { sh_tb = 4 * tid + b; break; }
          need -= (int)c;
        }
      }
      __syncthreads();
      if (sh_total >= K) { tb = sh_tb; break; }
      filt = 0u;
      __syncthreads();
    }

    const uint32_t cutk = (uint32_t)max(tb - 1, 0) << 20;
    if (tid == 0) sh_cnt = 0;
    __syncthreads();
    if (tid < pc) {
      if (fkey(rowp[tid]) >= cutk) {
        int p = atomicAdd(&sh_cnt, 1);
        if (p < CAND_CAP) cidx[p] = tid;
      }
    }
    for (int w = tid; w < nv4; w += NT) {
      float4 x = body[w];
      int base = pc + (w << 2);
      if (fkey(x.x) >= cutk) { int p = atomicAdd(&sh_cnt, 1); if (p < CAND_CAP) cidx[p] = base; }
      if (fkey(x.y) >= cutk) { int p = atomicAdd(&sh_cnt, 1); if (p < CAND_CAP) cidx[p] = base + 1; }
      if (fkey(x.z) >= cutk) { int p = atomicAdd(&sh_cnt, 1); if (p < CAND_CAP) cidx[p] = base + 2; }
      if (fkey(x.w) >= cutk) { int p = atomicAdd(&sh_cnt, 1); if (p < CAND_CAP) cidx[p] = base + 3; }
    }
    if (tid < tailc) {
      if (fkey(rowp[tailbase + tid]) >= cutk) {
        int p = atomicAdd(&sh_cnt, 1);
        if (p < CAND_CAP) cidx[p] = tailbase + tid;
      }
    }
    __syncthreads();
    const int C = min(sh_cnt, CAND_CAP);

    if (tid < C) {
      int idx = cidx[tid];
      float s = rowp[idx] / temp;
      ckey[tid] = fkey(s);
    }
    __syncthreads();

    if (tid < C) {
      const uint32_t mk = ckey[tid];
      const int mi = cidx[tid];
      int rank = 0;
      for (int j = 0; j < C; ++j) {
        uint32_t k = ckey[j];
        rank += (k > mk || (k == mk && cidx[j] < mi)) ? 1 : 0;
      }
      if (rank < K) {
        float s = rowp[mi] / temp;
        float v2 = s + gumbel_at((uint32_t)row * (uint32_t)VOCAB + (uint32_t)mi);
        bestv = v2; besti = mi;
      }
    }
    __syncthreads();
  }

  // ---- Common argmax reduction: wave shuffle + 16-way LDS combine ----
  for (int off = 32; off > 0; off >>= 1) {
    float v2 = __shfl_down(bestv, off);
    int i2 = __shfl_down(besti, off);
    if (v2 > bestv || (v2 == bestv && i2 < besti)) { bestv = v2; besti = i2; }
  }
  if (lane == 0) { wbv[wave] = bestv; wbi[wave] = besti; }
  __syncthreads();
  if (tid == 0) {
    float bv = wbv[0];
    int bi = wbi[0];
    for (int w = 1; w < 16; ++w) {
      float v2 = wbv[w];
      int i2 = wbi[w];
      if (v2 > bv || (v2 == bv && i2 < bi)) { bv = v2; bi = i2; }
    }
    out[row] = bi;
  }
}

extern "C" void kernel_launch(void* const* d_in, const int* in_sizes, int n_in,
                              void* d_out, int out_size, void* d_ws, size_t ws_size,
                              hipStream_t stream) {
  const float* logits = (const float*)d_in[0];
  const float* temp_p = (const float*)d_in[1];
  const int* topk_p = (const int*)d_in[2];
  int* out = (int*)d_out;
  hipLaunchKernelGGL(topk_sample_kernel, dim3(BATCH), dim3(NT), 0, stream,
                     logits, temp_p, topk_p, out);
}